// Round 1
// baseline (711.406 us; speedup 1.0000x reference)
//
#include <hip/hip_runtime.h>

// GCN 2-layer: h1 = relu(Â x W1 + b1), out = Â h1 W2 + b2
// where Â = D^-1/2 (A + I) D^-1/2.
// Factorization: hs = (x@W1)*dinv ; agg[d] = hs[d] + sum_{e:dst=d} hs[src] ;
// h1 = relu(agg*dinv + b1). Same for layer 2.

__global__ void count_kernel(const int* __restrict__ dst, int E,
                             int* __restrict__ count) {
    int i = blockIdx.x * blockDim.x + threadIdx.x;
    if (i < E) atomicAdd(&count[dst[i]], 1);
}

// One thread per row: h = x@W1 (W1 in LDS, broadcast reads), scale by dinv,
// write hs and agg-init (self-loop).
__global__ __launch_bounds__(256) void gemm1_kernel(
    const float* __restrict__ x, const float* __restrict__ W1,
    const int* __restrict__ count, float* __restrict__ dinv,
    float* __restrict__ hs, float* __restrict__ agg, int N) {
    __shared__ float4 Ws[64 * 16];  // W1[k][j] row-major, 16 float4 per k
    int t = threadIdx.x;
    const float4* W4 = (const float4*)W1;
    for (int i = t; i < 1024; i += 256) Ws[i] = W4[i];
    __syncthreads();
    int r = blockIdx.x * 256 + t;
    if (r >= N) return;
    float di = rsqrtf((float)(count[r] + 1));  // +1 self-loop; deg>=1 always
    dinv[r] = di;
    const float4* xrow = (const float4*)(x + (size_t)r * 64);
    float4 xv[16];
#pragma unroll
    for (int i = 0; i < 16; i++) xv[i] = xrow[i];
    float4 acc[16];
#pragma unroll
    for (int i = 0; i < 16; i++) acc[i] = make_float4(0.f, 0.f, 0.f, 0.f);
#pragma unroll
    for (int k = 0; k < 64; k++) {
        float xk = ((const float*)xv)[k];
#pragma unroll
        for (int j = 0; j < 16; j++) {
            float4 w = Ws[k * 16 + j];
            acc[j].x += xk * w.x; acc[j].y += xk * w.y;
            acc[j].z += xk * w.z; acc[j].w += xk * w.w;
        }
    }
    float4* hrow = (float4*)(hs + (size_t)r * 64);
    float4* arow = (float4*)(agg + (size_t)r * 64);
#pragma unroll
    for (int j = 0; j < 16; j++) {
        float4 v = acc[j];
        v.x *= di; v.y *= di; v.z *= di; v.w *= di;
        hrow[j] = v;
        arow[j] = v;
    }
}

// Wave-per-edge scatter: lane l handles feature l (64 features).
__global__ void scatter1_kernel(const int* __restrict__ src,
                                const int* __restrict__ dst,
                                const float* __restrict__ hs,
                                float* __restrict__ agg, int E) {
    int tid = blockIdx.x * blockDim.x + threadIdx.x;
    int l = tid & 63;
    int stride = (gridDim.x * blockDim.x) >> 6;
    for (int e = tid >> 6; e < E; e += stride) {
        int s = src[e];
        int d = dst[e];
        float v = hs[(size_t)s * 64 + l];
        unsafeAtomicAdd(&agg[(size_t)d * 64 + l], v);
    }
}

// Fused: h1 = relu(agg1*dinv + b1); g = h1@W2; gs = g*dinv; init out-acc.
__global__ __launch_bounds__(256) void gemm2_kernel(
    const float* __restrict__ agg1, const float* __restrict__ W2,
    const float* __restrict__ b1, const float* __restrict__ dinv,
    float* __restrict__ gs, float* __restrict__ outacc, int N) {
    __shared__ float4 Ws[64 * 8];  // W2[k][j], 8 float4 per k
    __shared__ float b1s[64];
    int t = threadIdx.x;
    const float4* W4 = (const float4*)W2;
    for (int i = t; i < 512; i += 256) Ws[i] = W4[i];
    if (t < 64) b1s[t] = b1[t];
    __syncthreads();
    int r = blockIdx.x * 256 + t;
    if (r >= N) return;
    float di = dinv[r];
    const float4* arow = (const float4*)(agg1 + (size_t)r * 64);
    float h2[64];
#pragma unroll
    for (int i = 0; i < 16; i++) {
        float4 v = arow[i];
        h2[4 * i + 0] = fmaxf(v.x * di + b1s[4 * i + 0], 0.f);
        h2[4 * i + 1] = fmaxf(v.y * di + b1s[4 * i + 1], 0.f);
        h2[4 * i + 2] = fmaxf(v.z * di + b1s[4 * i + 2], 0.f);
        h2[4 * i + 3] = fmaxf(v.w * di + b1s[4 * i + 3], 0.f);
    }
    float4 acc[8];
#pragma unroll
    for (int j = 0; j < 8; j++) acc[j] = make_float4(0.f, 0.f, 0.f, 0.f);
#pragma unroll
    for (int k = 0; k < 64; k++) {
        float hk = h2[k];
#pragma unroll
        for (int j = 0; j < 8; j++) {
            float4 w = Ws[k * 8 + j];
            acc[j].x += hk * w.x; acc[j].y += hk * w.y;
            acc[j].z += hk * w.z; acc[j].w += hk * w.w;
        }
    }
    float4* grow = (float4*)(gs + (size_t)r * 32);
    float4* orow = (float4*)(outacc + (size_t)r * 32);
#pragma unroll
    for (int j = 0; j < 8; j++) {
        float4 v = acc[j];
        v.x *= di; v.y *= di; v.z *= di; v.w *= di;
        grow[j] = v;
        orow[j] = v;
    }
}

// Half-wave-per-edge scatter: lane l handles feature l (32 features).
__global__ void scatter2_kernel(const int* __restrict__ src,
                                const int* __restrict__ dst,
                                const float* __restrict__ gs,
                                float* __restrict__ outacc, int E) {
    int tid = blockIdx.x * blockDim.x + threadIdx.x;
    int l = tid & 31;
    int stride = (gridDim.x * blockDim.x) >> 5;
    for (int e = tid >> 5; e < E; e += stride) {
        int s = src[e];
        int d = dst[e];
        float v = gs[(size_t)s * 32 + l];
        unsafeAtomicAdd(&outacc[(size_t)d * 32 + l], v);
    }
}

// out = out*dinv + b2 (per-row dinv, per-col b2). One thread per float4.
__global__ void final_kernel(float* __restrict__ out,
                             const float* __restrict__ dinv,
                             const float* __restrict__ b2, int N) {
    int i = blockIdx.x * blockDim.x + threadIdx.x;
    if (i >= N * 8) return;
    int r = i >> 3;
    int j4 = i & 7;
    float di = dinv[r];
    float4 b = ((const float4*)b2)[j4];
    float4 v = ((float4*)out)[i];
    v.x = v.x * di + b.x;
    v.y = v.y * di + b.y;
    v.z = v.z * di + b.z;
    v.w = v.w * di + b.w;
    ((float4*)out)[i] = v;
}

extern "C" void kernel_launch(void* const* d_in, const int* in_sizes, int n_in,
                              void* d_out, int out_size, void* d_ws,
                              size_t ws_size, hipStream_t stream) {
    const float* x  = (const float*)d_in[0];
    const int* ei   = (const int*)d_in[1];
    const float* W1 = (const float*)d_in[2];
    const float* b1 = (const float*)d_in[3];
    const float* W2 = (const float*)d_in[4];
    const float* b2 = (const float*)d_in[5];
    int N = in_sizes[0] / 64;
    int E = in_sizes[1] / 2;
    const int* src = ei;
    const int* dst = ei + E;

    char* ws = (char*)d_ws;
    int* count  = (int*)ws;                                      // N int
    float* dinv = (float*)(ws + (size_t)N * 4);                  // N f32
    float* hs   = (float*)(ws + (size_t)N * 8);                  // N*64 f32
    float* agg1 = (float*)(ws + (size_t)N * 8 + (size_t)N * 256);// N*64 f32
    float* gs2  = hs;  // hs dead after scatter1; reuse (N*32 f32)
    float* outp = (float*)d_out;                                 // N*32 f32

    hipMemsetAsync(count, 0, (size_t)N * 4, stream);
    count_kernel<<<(E + 255) / 256, 256, 0, stream>>>(dst, E, count);
    gemm1_kernel<<<(N + 255) / 256, 256, 0, stream>>>(x, W1, count, dinv, hs,
                                                      agg1, N);
    scatter1_kernel<<<2048, 256, 0, stream>>>(src, dst, hs, agg1, E);
    gemm2_kernel<<<(N + 255) / 256, 256, 0, stream>>>(agg1, W2, b1, dinv, gs2,
                                                      outp, N);
    scatter2_kernel<<<2048, 256, 0, stream>>>(src, dst, gs2, outp, E);
    final_kernel<<<(N * 8 + 255) / 256, 256, 0, stream>>>(outp, dinv, b2, N);
}

// Round 2
// 429.039 us; speedup vs baseline: 1.6581x; 1.6581x over previous
//
#include <hip/hip_runtime.h>

// GCN 2-layer: h1 = relu(Â x W1 + b1), out = Â h1 W2 + b2,  Â = D^-1/2 (A+I) D^-1/2
// Strategy: counting-sort edges by dst per call (int atomics only), then
// gather-only aggregation (no fp32 atomics — R1 showed those write through
// to HBM: 400 MB WRITE_SIZE on scatter1).
// Factorization: hs = (x@W1)*dinv ; h1 = relu((hs[d]+Σ_src hs[s])*dinv + b1)
//                gs = (h1@W2)*dinv ; out = (gs[d]+Σ_src gs[s])*dinv + b2

__global__ void count_kernel(const int* __restrict__ dst, int E,
                             int* __restrict__ count) {
    int i = blockIdx.x * blockDim.x + threadIdx.x;
    if (i < E) atomicAdd(&count[dst[i]], 1);
}

// Per-block inclusive Hillis-Steele scan of count; emits block sums.
__global__ __launch_bounds__(256) void scan1_kernel(
    const int* __restrict__ count, int* __restrict__ incl,
    int* __restrict__ bsum, int N) {
    __shared__ int s[256];
    int t = threadIdx.x;
    int i = blockIdx.x * 256 + t;
    int v0 = (i < N) ? count[i] : 0;
    s[t] = v0;
    __syncthreads();
#pragma unroll
    for (int d = 1; d < 256; d <<= 1) {
        int v = (t >= d) ? s[t - d] : 0;
        __syncthreads();
        s[t] += v;
        __syncthreads();
    }
    if (i < N) incl[i] = s[t];
    if (t == 255) bsum[blockIdx.x] = s[255];
}

// Single-block exclusive scan of block sums (nb <= 512).
__global__ __launch_bounds__(512) void scan2_kernel(int* __restrict__ bsum,
                                                    int nb) {
    __shared__ int s[512];
    int t = threadIdx.x;
    int v0 = (t < nb) ? bsum[t] : 0;
    s[t] = v0;
    __syncthreads();
#pragma unroll
    for (int d = 1; d < 512; d <<= 1) {
        int v = (t >= d) ? s[t - d] : 0;
        __syncthreads();
        s[t] += v;
        __syncthreads();
    }
    if (t < nb) bsum[t] = s[t] - v0;  // exclusive
}

// off[i] = exclusive prefix; cursor[i] = same (sort allocator).
__global__ void scan3_kernel(const int* __restrict__ count,
                             const int* __restrict__ incl,
                             const int* __restrict__ bsum,
                             int* __restrict__ off, int* __restrict__ cursor,
                             int N) {
    int i = blockIdx.x * 256 + threadIdx.x;
    if (i < N) {
        int o = bsum[blockIdx.x] + incl[i] - count[i];
        off[i] = o;
        cursor[i] = o;
    }
}

// Counting-sort scatter: ssrc holds src ids grouped by dst.
__global__ void sort_kernel(const int* __restrict__ src,
                            const int* __restrict__ dst,
                            int* __restrict__ cursor, int* __restrict__ ssrc,
                            int E) {
    int e = blockIdx.x * blockDim.x + threadIdx.x;
    if (e < E) {
        int d = dst[e];
        int pos = atomicAdd(&cursor[d], 1);
        ssrc[pos] = src[e];
    }
}

// One thread per row: hs = (x@W1)*dinv, dinv = rsqrt(deg+1). W1 in LDS.
__global__ __launch_bounds__(256) void gemm1_kernel(
    const float* __restrict__ x, const float* __restrict__ W1,
    const int* __restrict__ count, float* __restrict__ dinv,
    float* __restrict__ hs, int N) {
    __shared__ float4 Ws[64 * 16];
    int t = threadIdx.x;
    const float4* W4 = (const float4*)W1;
    for (int i = t; i < 1024; i += 256) Ws[i] = W4[i];
    __syncthreads();
    int r = blockIdx.x * 256 + t;
    if (r >= N) return;
    float di = rsqrtf((float)(count[r] + 1));
    dinv[r] = di;
    const float4* xrow = (const float4*)(x + (size_t)r * 64);
    float4 xv[16];
#pragma unroll
    for (int i = 0; i < 16; i++) xv[i] = xrow[i];
    float4 acc[16];
#pragma unroll
    for (int i = 0; i < 16; i++) acc[i] = make_float4(0.f, 0.f, 0.f, 0.f);
#pragma unroll
    for (int k = 0; k < 64; k++) {
        float xk = ((const float*)xv)[k];
#pragma unroll
        for (int j = 0; j < 16; j++) {
            float4 w = Ws[k * 16 + j];
            acc[j].x += xk * w.x; acc[j].y += xk * w.y;
            acc[j].z += xk * w.z; acc[j].w += xk * w.w;
        }
    }
    float4* hrow = (float4*)(hs + (size_t)r * 64);
#pragma unroll
    for (int j = 0; j < 16; j++) {
        float4 v = acc[j];
        v.x *= di; v.y *= di; v.z *= di; v.w *= di;
        hrow[j] = v;
    }
}

// Gather-aggregate layer 1: wave per node, lane = feature (64).
// h1 = relu((hs[d] + Σ hs[s]) * dinv + b1)
__global__ __launch_bounds__(256) void agg1_kernel(
    const float* __restrict__ hs, const int* __restrict__ ssrc,
    const int* __restrict__ off, const int* __restrict__ count,
    const float* __restrict__ dinv, const float* __restrict__ b1,
    float* __restrict__ h1, int N) {
    int w = (blockIdx.x * 256 + threadIdx.x) >> 6;
    int l = threadIdx.x & 63;
    if (w >= N) return;
    float acc = hs[(size_t)w * 64 + l];  // self-loop
    int base = off[w];
    int deg = count[w];
    int e = 0;
    for (; e + 4 <= deg; e += 4) {
        int s0 = ssrc[base + e + 0];
        int s1 = ssrc[base + e + 1];
        int s2 = ssrc[base + e + 2];
        int s3 = ssrc[base + e + 3];
        float v0 = hs[(size_t)s0 * 64 + l];
        float v1 = hs[(size_t)s1 * 64 + l];
        float v2 = hs[(size_t)s2 * 64 + l];
        float v3 = hs[(size_t)s3 * 64 + l];
        acc += (v0 + v1) + (v2 + v3);
    }
    for (; e < deg; e++) {
        int s = ssrc[base + e];
        acc += hs[(size_t)s * 64 + l];
    }
    h1[(size_t)w * 64 + l] = fmaxf(acc * dinv[w] + b1[l], 0.f);
}

// One thread per row: gs = (h1@W2)*dinv. W2 in LDS.
__global__ __launch_bounds__(256) void gemm2_kernel(
    const float* __restrict__ h1, const float* __restrict__ W2,
    const float* __restrict__ dinv, float* __restrict__ gs, int N) {
    __shared__ float4 Ws[64 * 8];
    int t = threadIdx.x;
    const float4* W4 = (const float4*)W2;
    for (int i = t; i < 512; i += 256) Ws[i] = W4[i];
    __syncthreads();
    int r = blockIdx.x * 256 + t;
    if (r >= N) return;
    float di = dinv[r];
    const float4* hrow = (const float4*)(h1 + (size_t)r * 64);
    float4 hv[16];
#pragma unroll
    for (int i = 0; i < 16; i++) hv[i] = hrow[i];
    float4 acc[8];
#pragma unroll
    for (int j = 0; j < 8; j++) acc[j] = make_float4(0.f, 0.f, 0.f, 0.f);
#pragma unroll
    for (int k = 0; k < 64; k++) {
        float hk = ((const float*)hv)[k];
#pragma unroll
        for (int j = 0; j < 8; j++) {
            float4 w = Ws[k * 8 + j];
            acc[j].x += hk * w.x; acc[j].y += hk * w.y;
            acc[j].z += hk * w.z; acc[j].w += hk * w.w;
        }
    }
    float4* grow = (float4*)(gs + (size_t)r * 32);
#pragma unroll
    for (int j = 0; j < 8; j++) {
        float4 v = acc[j];
        v.x *= di; v.y *= di; v.z *= di; v.w *= di;
        grow[j] = v;
    }
}

// Gather-aggregate layer 2: half-wave per node, lane = feature (32).
// out = (gs[d] + Σ gs[s]) * dinv + b2
__global__ __launch_bounds__(256) void agg2_kernel(
    const float* __restrict__ gs, const int* __restrict__ ssrc,
    const int* __restrict__ off, const int* __restrict__ count,
    const float* __restrict__ dinv, const float* __restrict__ b2,
    float* __restrict__ out, int N) {
    int w = (blockIdx.x * 256 + threadIdx.x) >> 5;
    int l = threadIdx.x & 31;
    if (w >= N) return;
    float acc = gs[(size_t)w * 32 + l];  // self-loop
    int base = off[w];
    int deg = count[w];
    int e = 0;
    for (; e + 4 <= deg; e += 4) {
        int s0 = ssrc[base + e + 0];
        int s1 = ssrc[base + e + 1];
        int s2 = ssrc[base + e + 2];
        int s3 = ssrc[base + e + 3];
        float v0 = gs[(size_t)s0 * 32 + l];
        float v1 = gs[(size_t)s1 * 32 + l];
        float v2 = gs[(size_t)s2 * 32 + l];
        float v3 = gs[(size_t)s3 * 32 + l];
        acc += (v0 + v1) + (v2 + v3);
    }
    for (; e < deg; e++) {
        int s = ssrc[base + e];
        acc += gs[(size_t)s * 32 + l];
    }
    out[(size_t)w * 32 + l] = acc * dinv[w] + b2[l];
}

extern "C" void kernel_launch(void* const* d_in, const int* in_sizes, int n_in,
                              void* d_out, int out_size, void* d_ws,
                              size_t ws_size, hipStream_t stream) {
    const float* x  = (const float*)d_in[0];
    const int* ei   = (const int*)d_in[1];
    const float* W1 = (const float*)d_in[2];
    const float* b1 = (const float*)d_in[3];
    const float* W2 = (const float*)d_in[4];
    const float* b2 = (const float*)d_in[5];
    int N = in_sizes[0] / 64;
    int E = in_sizes[1] / 2;
    const int* src = ei;
    const int* dst = ei + E;
    int nb = (N + 255) / 256;  // <= 512 required by scan2

    char* ws = (char*)d_ws;
    size_t o = 0;
    int* count  = (int*)(ws + o); o += (size_t)N * 4;
    int* incl   = (int*)(ws + o); o += (size_t)N * 4;
    int* bsum   = (int*)(ws + o); o += 512 * 4;
    int* off    = (int*)(ws + o); o += (size_t)N * 4;
    int* cursor = (int*)(ws + o); o += (size_t)N * 4;
    float* dinv = (float*)(ws + o); o += (size_t)N * 4;
    int* ssrc   = (int*)(ws + o); o += (size_t)E * 4;
    float* hs   = (float*)(ws + o); o += (size_t)N * 64 * 4;
    float* h1   = (float*)(ws + o); o += (size_t)N * 64 * 4;
    float* gs   = hs;  // hs dead after agg1; reuse for layer-2 (N*32 f32)
    float* outp = (float*)d_out;

    hipMemsetAsync(count, 0, (size_t)N * 4, stream);
    count_kernel<<<(E + 255) / 256, 256, 0, stream>>>(dst, E, count);
    scan1_kernel<<<nb, 256, 0, stream>>>(count, incl, bsum, N);
    scan2_kernel<<<1, 512, 0, stream>>>(bsum, nb);
    scan3_kernel<<<nb, 256, 0, stream>>>(count, incl, bsum, off, cursor, N);
    sort_kernel<<<(E + 255) / 256, 256, 0, stream>>>(src, dst, cursor, ssrc, E);
    gemm1_kernel<<<(N + 255) / 256, 256, 0, stream>>>(x, W1, count, dinv, hs, N);
    agg1_kernel<<<(N * 64 + 255) / 256, 256, 0, stream>>>(hs, ssrc, off, count,
                                                          dinv, b1, h1, N);
    gemm2_kernel<<<(N + 255) / 256, 256, 0, stream>>>(h1, W2, dinv, gs, N);
    agg2_kernel<<<(N * 32 + 255) / 256, 256, 0, stream>>>(gs, ssrc, off, count,
                                                          dinv, b2, outp, N);
}